// Round 10
// baseline (284.728 us; speedup 1.0000x reference)
//
#include <hip/hip_runtime.h>
#include <hip/hip_bf16.h>

// Transformer block: x[2,2048,768] fp32. GEMMs bf16 MFMA 16x16x32, 64x128
// tiles (4 waves of 32x64), BK=64, fp32 accumulate. N=768 GEMMs (Wo, FF2)
// split-K=2 with bf16 partials. QKV epilogue writes V directly transposed.
// Attention v6: one block = 64 q-rows x ALL 2048 keys (no key split, no
// reduce pass); round-5 inner loop (KV-chunk 64, 136B-padded V rows, 0
// conflicts); bf16 mask bias; normalized output written via LDS transpose.

typedef unsigned short u16;
typedef unsigned int u32;
typedef __attribute__((ext_vector_type(8))) short s16x8;   // 8 bf16 (4 VGPR)
typedef __attribute__((ext_vector_type(4))) short s16x4;   // 4 bf16 (2 VGPR)
typedef __attribute__((ext_vector_type(4))) float fx4;     // 4 fp32 acc

#define D_MODEL 768
#define NH 12
#define HS 64
#define TT 2048
#define BB 2

__device__ __forceinline__ u16 f2bf(float f) {
  union { float f; u32 u; } v; v.f = f;
  u32 r = v.u + 0x7fffu + ((v.u >> 16) & 1u);   // RNE
  return (u16)(r >> 16);
}
__device__ __forceinline__ float bf2f(u16 h) {
  union { u32 u; float f; } v; v.u = ((u32)h) << 16; return v.f;
}
__device__ __forceinline__ s16x4 pack4(float a, float b, float c, float d) {
  union { __hip_bfloat162 h2[2]; s16x4 v; } u;
  u.h2[0] = __float22bfloat162_rn({a, b});
  u.h2[1] = __float22bfloat162_rn({c, d});
  return u.v;
}

// async global->LDS, 16B per lane; LDS dest = wave-uniform base + lane*16
__device__ __forceinline__ void async16(const void* g, void* l) {
  __builtin_amdgcn_global_load_lds(
      (const __attribute__((address_space(1))) u32*)g,
      (__attribute__((address_space(3))) u32*)l, 16, 0, 0);
}

// ---------------- mega preprocessing kernel --------------------------------
// blocks [0,6912): weight transpose+convert tiles (Wq,Wk,Wv,Wo,W1,W2)
// blocks [6912,11008): LayerNorm1 rows      blocks [11008,11024): mask bias
__global__ __launch_bounds__(256) void preproc(
    const float* __restrict__ x, const int* __restrict__ mask,
    const float* __restrict__ Wq, const float* __restrict__ Wk,
    const float* __restrict__ Wv, const float* __restrict__ Wo,
    const float* __restrict__ W1, const float* __restrict__ W2,
    const float* __restrict__ g1, const float* __restrict__ be1,
    u16* __restrict__ WqkvT, u16* __restrict__ WoT,
    u16* __restrict__ W1T, u16* __restrict__ W2T,
    u16* __restrict__ h1, u16* __restrict__ mb) {
  __shared__ float t[32][33];
  __shared__ float ss[4], ssq[4];
  const int bid = blockIdx.x, tid = threadIdx.x;
  if (bid < 6912) {
    const float* in; u16* out; int R, C, cx, cy;
    if (bid < 1728) {
      int wsel = bid / 576, s = bid % 576;
      in = wsel == 0 ? Wq : wsel == 1 ? Wk : Wv;
      out = WqkvT + (size_t)wsel * 768 * 768;
      R = 768; C = 768; cx = s % 24; cy = s / 24;
    } else if (bid < 2304) {
      int s = bid - 1728; in = Wo; out = WoT;
      R = 768; C = 768; cx = s % 24; cy = s / 24;
    } else if (bid < 4608) {
      int s = bid - 2304; in = W1; out = W1T;
      R = 768; C = 3072; cx = s % 96; cy = s / 96;
    } else {
      int s = bid - 4608; in = W2; out = W2T;
      R = 3072; C = 768; cx = s % 24; cy = s / 24;
    }
    int c0 = cx * 32, r0 = cy * 32, xx = tid & 31, yy = tid >> 5;
    for (int i = 0; i < 4; i++)
      t[yy + i * 8][xx] = in[(size_t)(r0 + yy + i * 8) * C + c0 + xx];
    __syncthreads();
    for (int i = 0; i < 4; i++)
      out[(size_t)(c0 + yy + i * 8) * R + r0 + xx] = f2bf(t[xx][yy + i * 8]);
  } else if (bid < 11008) {
    int row = bid - 6912;
    const float* xr = x + (size_t)row * D_MODEL;
    float v0 = xr[tid], v1 = xr[tid + 256], v2 = xr[tid + 512];
    float s = v0 + v1 + v2, sq = v0 * v0 + v1 * v1 + v2 * v2;
    for (int m = 1; m < 64; m <<= 1) { s += __shfl_xor(s, m); sq += __shfl_xor(sq, m); }
    int w = tid >> 6;
    if ((tid & 63) == 0) { ss[w] = s; ssq[w] = sq; }
    __syncthreads();
    s = ss[0] + ss[1] + ss[2] + ss[3];
    sq = ssq[0] + ssq[1] + ssq[2] + ssq[3];
    float mean = s * (1.f / D_MODEL);
    float var = sq * (1.f / D_MODEL) - mean * mean;
    float rstd = rsqrtf(var + 1e-5f);
    u16* orow = h1 + (size_t)row * D_MODEL;
    orow[tid]       = f2bf((v0 - mean) * rstd * g1[tid]       + be1[tid]);
    orow[tid + 256] = f2bf((v1 - mean) * rstd * g1[tid + 256] + be1[tid + 256]);
    orow[tid + 512] = f2bf((v2 - mean) * rstd * g1[tid + 512] + be1[tid + 512]);
  } else {
    int i = (bid - 11008) * 256 + tid;
    mb[i] = mask[i] ? (u16)0 : f2bf(-1e30f);
  }
}

// ---- partial-sum(2, bf16) + residual + bias + LayerNorm -> yv fp32, h2 bf16
__global__ __launch_bounds__(256) void red_wo_ln(
    const u16* __restrict__ p0, const u16* __restrict__ p1,
    const float* __restrict__ x, const float* __restrict__ bo,
    const float* __restrict__ g, const float* __restrict__ be,
    float* __restrict__ yv, u16* __restrict__ h2) {
  int row = blockIdx.x, tid = threadIdx.x;
  size_t base = (size_t)row * D_MODEL;
  float v[3];
  float s = 0.f, sq = 0.f;
  for (int i = 0; i < 3; i++) {
    int c = tid + i * 256;
    size_t idx = base + c;
    float t = bf2f(p0[idx]) + bf2f(p1[idx]) + x[idx] + bo[c];
    v[i] = t; yv[idx] = t;
    s += t; sq += t * t;
  }
  for (int m = 1; m < 64; m <<= 1) { s += __shfl_xor(s, m); sq += __shfl_xor(sq, m); }
  __shared__ float ss[4], ssq[4];
  int w = tid >> 6;
  if ((tid & 63) == 0) { ss[w] = s; ssq[w] = sq; }
  __syncthreads();
  s = ss[0] + ss[1] + ss[2] + ss[3];
  sq = ssq[0] + ssq[1] + ssq[2] + ssq[3];
  float mean = s * (1.f / D_MODEL);
  float var = sq * (1.f / D_MODEL) - mean * mean;
  float rstd = rsqrtf(var + 1e-5f);
  for (int i = 0; i < 3; i++) {
    int c = tid + i * 256;
    h2[base + c] = f2bf((v[i] - mean) * rstd * g[c] + be[c]);
  }
}

// ---- partial-sum(2, bf16) + residual + bias -> out fp32 (vectorized x4) ---
__global__ __launch_bounds__(256) void red_ff2(
    const u16* __restrict__ p0, const u16* __restrict__ p1,
    const float* __restrict__ yv,
    const float* __restrict__ bias, float* __restrict__ out) {
  size_t i = ((size_t)blockIdx.x * 256 + threadIdx.x) * 4;
  int col = (int)(i % D_MODEL);
  ushort4 a = *(const ushort4*)(p0 + i);
  ushort4 b = *(const ushort4*)(p1 + i);
  float4 y = *(const float4*)(yv + i);
  float4 o;
  o.x = bf2f(a.x) + bf2f(b.x) + y.x + bias[col];
  o.y = bf2f(a.y) + bf2f(b.y) + y.y + bias[col + 1];
  o.z = bf2f(a.z) + bf2f(b.z) + y.z + bias[col + 2];
  o.w = bf2f(a.w) + bf2f(b.w) + y.w + bias[col + 3];
  *(float4*)(out + i) = o;
}

// ---------------- GEMM: C[M][N] = A[M][K](bf16) * Bt[N][K](bf16)^T ---------
// 64x128 tile, BK=64, 4 waves 2x2 (wave tile 32x64, acc 2x4).
template <int EPI>
__global__ __launch_bounds__(256) void gemm_bt(
    const u16* __restrict__ A, const u16* __restrict__ Bt,
    int M, int N, int K,
    u16* __restrict__ outb, const float* __restrict__ bias,
    float qs, u16* __restrict__ vtp,
    u16* __restrict__ p0, u16* __restrict__ p1) {
  __shared__ __align__(16) u16 lA[64 * 64];    //  8 KB, 8 chunks/row, xor-swz
  __shared__ __align__(16) u16 lB[128 * 64];   // 16 KB
  const int tid = threadIdx.x;
  const int lane = tid & 63, w = tid >> 6;
  const int quad = lane >> 4, l15 = lane & 15;
  const int wm = w >> 1, wn = w & 1;
  const int bm = blockIdx.y, bn = blockIdx.x;
  const int Ksub = K / gridDim.z;
  const int k0 = blockIdx.z * Ksub;

  fx4 acc[2][4] = {};

  for (int kt = k0; kt < k0 + Ksub; kt += 64) {
    __syncthreads();
    #pragma unroll
    for (int t = 0; t < 2; t++) {
      int p = t * 256 + tid;
      int m = p >> 3, qp = p & 7, ql = qp ^ (m & 7);
      async16(A + (size_t)(bm * 64 + m) * K + kt + ql * 8,
              (char*)lA + t * 4096 + w * 1024);
    }
    #pragma unroll
    for (int t = 0; t < 4; t++) {
      int p = t * 256 + tid;
      int n = p >> 3, qp = p & 7, ql = qp ^ (n & 7);
      async16(Bt + (size_t)(bn * 128 + n) * K + kt + ql * 8,
              (char*)lB + t * 4096 + w * 1024);
    }
    __syncthreads();
    #pragma unroll
    for (int kk = 0; kk < 2; kk++) {
      s16x8 af[2], bfr[4];
      #pragma unroll
      for (int i = 0; i < 2; i++) {
        int m = wm * 32 + i * 16 + l15;
        af[i] = *(const s16x8*)((const char*)lA + m * 128 +
                                (((kk * 4 + quad) ^ (m & 7)) * 16));
      }
      #pragma unroll
      for (int j = 0; j < 4; j++) {
        int n = wn * 64 + j * 16 + l15;
        bfr[j] = *(const s16x8*)((const char*)lB + n * 128 +
                                 (((kk * 4 + quad) ^ (n & 7)) * 16));
      }
      #pragma unroll
      for (int i = 0; i < 2; i++)
        #pragma unroll
        for (int j = 0; j < 4; j++)
          acc[i][j] = __builtin_amdgcn_mfma_f32_16x16x32_bf16(af[i], bfr[j], acc[i][j], 0, 0, 0);
    }
  }

  u16* pb = (EPI == 3) ? (blockIdx.z == 0 ? p0 : p1) : nullptr;

  #pragma unroll
  for (int i = 0; i < 2; i++)
    #pragma unroll
    for (int j = 0; j < 4; j++) {
      int row0 = bm * 64 + wm * 32 + i * 16 + quad * 4;
      int col = bn * 128 + wn * 64 + j * 16 + l15;
      if (EPI == 0) {
        if (vtp != nullptr && col >= 1536) {
          // V region -> transposed store: Vt[(b*768 + col-1536)][tok]
          int bb = row0 >> 11, t0 = row0 & 2047;
          ushort4 pk = {f2bf(acc[i][j][0]), f2bf(acc[i][j][1]),
                        f2bf(acc[i][j][2]), f2bf(acc[i][j][3])};
          *(ushort4*)(vtp + ((size_t)(bb * 768 + (col - 1536)) << 11) + t0) = pk;
        } else {
          float sc = (col < 768) ? qs : 1.f;
          for (int r = 0; r < 4; r++)
            outb[(size_t)(row0 + r) * N + col] = f2bf(acc[i][j][r] * sc);
        }
      } else if (EPI == 2) {
        for (int r = 0; r < 4; r++)
          outb[(size_t)(row0 + r) * N + col] = f2bf(fmaxf(acc[i][j][r] + bias[col], 0.f));
      } else {
        for (int r = 0; r < 4; r++)
          pb[(size_t)(row0 + r) * N + col] = f2bf(acc[i][j][r]);
      }
    }
}

// ---------------- Flash attention v6: full-key blocks, self-normalizing ----
// grid (qt=32, bh=24), 256 threads (4 waves). Block: 64 q-rows x 2048 keys
// (32 iters of 64). Wave w owns q = w*16 + l15. No partials, no reduce pass.
__global__ __launch_bounds__(256) void attn_kernel(
    const u16* __restrict__ qkv, const u16* __restrict__ vt,
    const u16* __restrict__ maskadd, u16* __restrict__ out) {
  __shared__ __align__(16) u16 sQ[64 * 64];      // 8 KB, xor-swizzled chunks
  __shared__ __align__(16) u16 sK[64 * 64];      // 8 KB, xor-swizzled chunks
  __shared__ __align__(16) u16 sV[64 * 68];      // 8.5 KB, 136B padded rows
  __shared__ __align__(16) u16 smask[2048];      // 4 KB bf16 bias
  const int bh = blockIdx.y, b = bh / NH, h = bh % NH;
  const int qt = blockIdx.x;
  const int tid = threadIdx.x, lane = tid & 63, w = tid >> 6;
  const int quad = lane >> 4, l15 = lane & 15;

  // stage Q (64 rows x 64): 512 chunks, swizzle qp ^ (m&7)
  #pragma unroll
  for (int i = 0; i < 2; i++) {
    int p = i * 256 + tid;
    int m = p >> 3, qp = p & 7, ql = qp ^ (m & 7);
    async16(qkv + (size_t)(b * TT + qt * 64 + m) * 2304 + h * HS + ql * 8,
            (char*)sQ + i * 4096 + w * 1024);
  }
  #pragma unroll
  for (int j = 0; j < 8; j++)
    smask[j * 256 + tid] = maskadd[b * TT + j * 256 + tid];
  // V register prefetch: rows vr=tid>>3 and vr+32, chunk vc=tid&7
  const int vr = tid >> 3, vc = tid & 7;
  const u16* vb0 = vt + ((size_t)bh * HS + vr) * TT;
  const u16* vb1 = vt + ((size_t)bh * HS + vr + 32) * TT;
  s16x8 vcur0 = *(const s16x8*)(vb0 + vc * 8);
  s16x8 vcur1 = *(const s16x8*)(vb1 + vc * 8);
  __syncthreads();

  // Q B-frags: q-row = w*16 + l15
  const int qrow = w * 16 + l15;
  s16x8 aq0 = *(const s16x8*)((const char*)sQ + qrow * 128 + ((quad ^ (l15 & 7)) * 16));
  s16x8 aq1 = *(const s16x8*)((const char*)sQ + qrow * 128 + (((4 + quad) ^ (l15 & 7)) * 16));

  const char* pK0 = (const char*)sK + l15 * 128 + ((quad ^ (l15 & 7)) * 16);
  const char* pK1 = (const char*)sK + l15 * 128 + (((4 + quad) ^ (l15 & 7)) * 16);
  const char* pV  = (const char*)sV + l15 * 136 + quad * 8;
  char* vw0 = (char*)sV + vr * 136 + vc * 16;
  char* vw1 = vw0 + 32 * 136;

  float lsum = 0.f;
  fx4 o[4] = {};

  for (int kc = 0; kc < 32; kc++) {
    __syncthreads();
    #pragma unroll
    for (int i = 0; i < 2; i++) {   // stage K chunk (64 keys x 64 hs)
      int p = i * 256 + tid;
      int m = p >> 3, qp = p & 7, ql = qp ^ (m & 7);
      async16(qkv + (size_t)(b * TT + kc * 64 + m) * 2304 + D_MODEL + h * HS + ql * 8,
              (char*)sK + i * 4096 + w * 1024);
    }
    *(s16x8*)vw0 = vcur0;           // V tile (padded rows) from registers
    *(s16x8*)vw1 = vcur1;
    __syncthreads();
    int kn = (kc < 31 ? kc + 1 : kc) * 64;
    s16x8 vn0 = *(const s16x8*)(vb0 + kn + vc * 8);
    s16x8 vn1 = *(const s16x8*)(vb1 + kn + vc * 8);

    #pragma unroll
    for (int kt = 0; kt < 4; kt++) {
      ushort4 mk = *(const ushort4*)&smask[kc * 64 + kt * 16 + quad * 4];
      fx4 s = {bf2f(mk.x), bf2f(mk.y), bf2f(mk.z), bf2f(mk.w)};
      s16x8 ak0 = *(const s16x8*)(pK0 + kt * 2048);
      s16x8 ak1 = *(const s16x8*)(pK1 + kt * 2048);
      s = __builtin_amdgcn_mfma_f32_16x16x32_bf16(ak0, aq0, s, 0, 0, 0);
      s = __builtin_amdgcn_mfma_f32_16x16x32_bf16(ak1, aq1, s, 0, 0, 0);
      float e0 = __builtin_amdgcn_exp2f(s[0]);
      float e1 = __builtin_amdgcn_exp2f(s[1]);
      float e2 = __builtin_amdgcn_exp2f(s[2]);
      float e3 = __builtin_amdgcn_exp2f(s[3]);
      lsum += (e0 + e1) + (e2 + e3);
      s16x4 pB = pack4(e0, e1, e2, e3);
      #pragma unroll
      for (int jv = 0; jv < 4; jv++) {
        s16x4 av = *(const s16x4*)(pV + jv * 2176 + kt * 32);
        o[jv] = __builtin_amdgcn_mfma_f32_16x16x16bf16_1k(av, pB, o[jv], 0, 0, 0);
      }
    }
    vcur0 = vn0; vcur1 = vn1;
  }

  // full key-sum per q (= l15): reduce over quads
  lsum += __shfl_xor(lsum, 16);
  lsum += __shfl_xor(lsum, 32);
  float rinv = 1.f / lsum;

  // normalized O^T -> LDS transpose (reuse sV; pitch 68 u16), then coalesced
  // 16B stores. NOTE: column index must include the wave's q offset (w*16).
  __syncthreads();
  u16* sT = sV;
  #pragma unroll
  for (int jv = 0; jv < 4; jv++)
    #pragma unroll
    for (int r = 0; r < 4; r++) {
      int vd = jv * 16 + quad * 4 + r;
      sT[vd * 68 + w * 16 + l15] = f2bf(o[jv][r] * rinv);
    }
  __syncthreads();
  int q = tid >> 2, c = tid & 3;
  u16* orow = out + (size_t)(b * TT + qt * 64 + q) * D_MODEL + h * HS + c * 16;
  s16x8 o0, o1;
  #pragma unroll
  for (int i = 0; i < 8; i++) o0[i] = (short)sT[(c * 16 + i) * 68 + q];
  #pragma unroll
  for (int i = 0; i < 8; i++) o1[i] = (short)sT[(c * 16 + 8 + i) * 68 + q];
  *(s16x8*)orow = o0;
  *(s16x8*)(orow + 8) = o1;
}

extern "C" void kernel_launch(void* const* d_in, const int* in_sizes, int n_in,
                              void* d_out, int out_size, void* d_ws, size_t ws_size,
                              hipStream_t stream) {
  const float* x    = (const float*)d_in[0];
  const int*   mask = (const int*)d_in[1];
  const float* Wq   = (const float*)d_in[2];
  const float* Wk   = (const float*)d_in[3];
  const float* Wv   = (const float*)d_in[4];
  const float* Wo   = (const float*)d_in[5];
  const float* bo   = (const float*)d_in[6];
  const float* g1   = (const float*)d_in[7];
  const float* be1  = (const float*)d_in[8];
  const float* g2   = (const float*)d_in[9];
  const float* be2  = (const float*)d_in[10];
  const float* W1   = (const float*)d_in[11];
  const float* bb1  = (const float*)d_in[12];
  const float* W2   = (const float*)d_in[13];
  const float* bb2  = (const float*)d_in[14];
  float* out = (float*)d_out;
  char* ws = (char*)d_ws;

  // workspace carve (bytes), total 64,503,808
  u16*   WqkvT = (u16*)(ws + 0);           //  3,538,944  [2304][768]
  u16*   WoT   = (u16*)(ws + 3538944);     //  1,179,648  [768][768]
  u16*   W1T   = (u16*)(ws + 4718592);     //  4,718,592  [3072][768]
  u16*   W2T   = (u16*)(ws + 9437184);     //  4,718,592  [768][3072]
  u16*   h1    = (u16*)(ws + 14155776);    //  6,291,456  [4096][768]; h2 alias
  u16*   QKV   = (u16*)(ws + 20447232);    // 18,874,368  [4096][2304]
  u16*   Vt    = (u16*)(ws + 39321600);    //  6,291,456  [24][64][2048]
  u16*   attn  = (u16*)(ws + 45613056);    //  6,291,456  [4096][768]
  float* yv    = (float*)(ws + 51904512);  // 12,582,912  [4096][768]
  u16*   mbias = (u16*)(ws + 51904512);    // 8,192 B bf16; dead before yv use
  u16*   h2    = h1;
  u16*   ff1   = QKV;                      // 25.17 MB spans QKV+Vt
  // Wo partials (2 x 6,291,456): QKV span (dead after attn)
  u16* pw0 = (u16*)(ws + 20447232);
  u16* pw1 = (u16*)(ws + 26738688);
  // FF2 partials (2 x 6,291,456)
  u16* pf0 = (u16*)(ws + 0);               // weight-head span (dead)
  u16* pf1 = (u16*)(ws + 14155776);        // h2 (dead after FF1)

  const float QS = 0.05205875399f;  // 768^-0.5 * log2(e)

  preproc<<<11024, 256, 0, stream>>>(x, mask, Wq, Wk, Wv, Wo, W1, W2,
                                     g1, be1, WqkvT, WoT, W1T, W2T, h1, mbias);
  // QKV: Q (scaled), K into QKV buffer; V directly transposed to Vt
  gemm_bt<0><<<dim3(18, 64, 1), 256, 0, stream>>>(h1, WqkvT, 4096, 2304, 768,
      QKV, nullptr, QS, Vt, nullptr, nullptr);
  attn_kernel<<<dim3(32, 24), 256, 0, stream>>>(QKV, Vt, mbias, attn);
  // Wo: split-K=2 -> 768 blocks, Ksub=384
  gemm_bt<3><<<dim3(6, 64, 2), 256, 0, stream>>>(attn, WoT, 4096, 768, 768,
      nullptr, nullptr, 1.f, nullptr, pw0, pw1);
  red_wo_ln<<<4096, 256, 0, stream>>>(pw0, pw1, x, bo, g2, be2, yv, h2);
  gemm_bt<2><<<dim3(24, 64, 1), 256, 0, stream>>>(h2, W1T, 4096, 3072, 768,
      ff1, bb1, 1.f, nullptr, nullptr, nullptr);
  // FF2: split-K=2 -> 768 blocks, Ksub=1536
  gemm_bt<3><<<dim3(6, 64, 2), 256, 0, stream>>>(ff1, W2T, 4096, 768, 3072,
      nullptr, nullptr, 1.f, nullptr, pf0, pf1);
  red_ff2<<<3072, 256, 0, stream>>>(pf0, pf1, yv, bb2, out);
}

// Round 11
// 279.298 us; speedup vs baseline: 1.0194x; 1.0194x over previous
//
#include <hip/hip_runtime.h>
#include <hip/hip_bf16.h>

// Transformer block: x[2,2048,768] fp32. GEMMs bf16 MFMA 16x16x32, 64x128
// tiles (4 waves of 32x64), BK=64, fp32 accumulate. N=768 GEMMs (Wo, FF2)
// split-K=2 with bf16 partials. QKV epilogue writes V directly transposed.
// Attention v7: 512-thread blocks, 64 q-rows x 2048 keys; wave-group g
// (4 waves) handles keys [g*1024, g*1024+1024) with its own sK/sV buffers
// (round-5 inner loop: KV-chunk 64, 136B-padded V rows, 0 conflicts).
// Halves combined in-block via LDS; self-normalizing; no reduce pass.

typedef unsigned short u16;
typedef unsigned int u32;
typedef __attribute__((ext_vector_type(8))) short s16x8;   // 8 bf16 (4 VGPR)
typedef __attribute__((ext_vector_type(4))) short s16x4;   // 4 bf16 (2 VGPR)
typedef __attribute__((ext_vector_type(4))) float fx4;     // 4 fp32 acc

#define D_MODEL 768
#define NH 12
#define HS 64
#define TT 2048
#define BB 2

__device__ __forceinline__ u16 f2bf(float f) {
  union { float f; u32 u; } v; v.f = f;
  u32 r = v.u + 0x7fffu + ((v.u >> 16) & 1u);   // RNE
  return (u16)(r >> 16);
}
__device__ __forceinline__ float bf2f(u16 h) {
  union { u32 u; float f; } v; v.u = ((u32)h) << 16; return v.f;
}
__device__ __forceinline__ s16x4 pack4(float a, float b, float c, float d) {
  union { __hip_bfloat162 h2[2]; s16x4 v; } u;
  u.h2[0] = __float22bfloat162_rn({a, b});
  u.h2[1] = __float22bfloat162_rn({c, d});
  return u.v;
}

// async global->LDS, 16B per lane; LDS dest = wave-uniform base + lane*16
__device__ __forceinline__ void async16(const void* g, void* l) {
  __builtin_amdgcn_global_load_lds(
      (const __attribute__((address_space(1))) u32*)g,
      (__attribute__((address_space(3))) u32*)l, 16, 0, 0);
}

// ---------------- mega preprocessing kernel --------------------------------
// blocks [0,6912): weight transpose+convert tiles (Wq,Wk,Wv,Wo,W1,W2)
// blocks [6912,11008): LayerNorm1 rows      blocks [11008,11024): mask bias
__global__ __launch_bounds__(256) void preproc(
    const float* __restrict__ x, const int* __restrict__ mask,
    const float* __restrict__ Wq, const float* __restrict__ Wk,
    const float* __restrict__ Wv, const float* __restrict__ Wo,
    const float* __restrict__ W1, const float* __restrict__ W2,
    const float* __restrict__ g1, const float* __restrict__ be1,
    u16* __restrict__ WqkvT, u16* __restrict__ WoT,
    u16* __restrict__ W1T, u16* __restrict__ W2T,
    u16* __restrict__ h1, u16* __restrict__ mb) {
  __shared__ float t[32][33];
  __shared__ float ss[4], ssq[4];
  const int bid = blockIdx.x, tid = threadIdx.x;
  if (bid < 6912) {
    const float* in; u16* out; int R, C, cx, cy;
    if (bid < 1728) {
      int wsel = bid / 576, s = bid % 576;
      in = wsel == 0 ? Wq : wsel == 1 ? Wk : Wv;
      out = WqkvT + (size_t)wsel * 768 * 768;
      R = 768; C = 768; cx = s % 24; cy = s / 24;
    } else if (bid < 2304) {
      int s = bid - 1728; in = Wo; out = WoT;
      R = 768; C = 768; cx = s % 24; cy = s / 24;
    } else if (bid < 4608) {
      int s = bid - 2304; in = W1; out = W1T;
      R = 768; C = 3072; cx = s % 96; cy = s / 96;
    } else {
      int s = bid - 4608; in = W2; out = W2T;
      R = 3072; C = 768; cx = s % 24; cy = s / 24;
    }
    int c0 = cx * 32, r0 = cy * 32, xx = tid & 31, yy = tid >> 5;
    for (int i = 0; i < 4; i++)
      t[yy + i * 8][xx] = in[(size_t)(r0 + yy + i * 8) * C + c0 + xx];
    __syncthreads();
    for (int i = 0; i < 4; i++)
      out[(size_t)(c0 + yy + i * 8) * R + r0 + xx] = f2bf(t[xx][yy + i * 8]);
  } else if (bid < 11008) {
    int row = bid - 6912;
    const float* xr = x + (size_t)row * D_MODEL;
    float v0 = xr[tid], v1 = xr[tid + 256], v2 = xr[tid + 512];
    float s = v0 + v1 + v2, sq = v0 * v0 + v1 * v1 + v2 * v2;
    for (int m = 1; m < 64; m <<= 1) { s += __shfl_xor(s, m); sq += __shfl_xor(sq, m); }
    int w = tid >> 6;
    if ((tid & 63) == 0) { ss[w] = s; ssq[w] = sq; }
    __syncthreads();
    s = ss[0] + ss[1] + ss[2] + ss[3];
    sq = ssq[0] + ssq[1] + ssq[2] + ssq[3];
    float mean = s * (1.f / D_MODEL);
    float var = sq * (1.f / D_MODEL) - mean * mean;
    float rstd = rsqrtf(var + 1e-5f);
    u16* orow = h1 + (size_t)row * D_MODEL;
    orow[tid]       = f2bf((v0 - mean) * rstd * g1[tid]       + be1[tid]);
    orow[tid + 256] = f2bf((v1 - mean) * rstd * g1[tid + 256] + be1[tid + 256]);
    orow[tid + 512] = f2bf((v2 - mean) * rstd * g1[tid + 512] + be1[tid + 512]);
  } else {
    int i = (bid - 11008) * 256 + tid;
    mb[i] = mask[i] ? (u16)0 : f2bf(-1e30f);
  }
}

// ---- partial-sum(2, bf16) + residual + bias + LayerNorm -> yv fp32, h2 bf16
__global__ __launch_bounds__(256) void red_wo_ln(
    const u16* __restrict__ p0, const u16* __restrict__ p1,
    const float* __restrict__ x, const float* __restrict__ bo,
    const float* __restrict__ g, const float* __restrict__ be,
    float* __restrict__ yv, u16* __restrict__ h2) {
  int row = blockIdx.x, tid = threadIdx.x;
  size_t base = (size_t)row * D_MODEL;
  float v[3];
  float s = 0.f, sq = 0.f;
  for (int i = 0; i < 3; i++) {
    int c = tid + i * 256;
    size_t idx = base + c;
    float t = bf2f(p0[idx]) + bf2f(p1[idx]) + x[idx] + bo[c];
    v[i] = t; yv[idx] = t;
    s += t; sq += t * t;
  }
  for (int m = 1; m < 64; m <<= 1) { s += __shfl_xor(s, m); sq += __shfl_xor(sq, m); }
  __shared__ float ss[4], ssq[4];
  int w = tid >> 6;
  if ((tid & 63) == 0) { ss[w] = s; ssq[w] = sq; }
  __syncthreads();
  s = ss[0] + ss[1] + ss[2] + ss[3];
  sq = ssq[0] + ssq[1] + ssq[2] + ssq[3];
  float mean = s * (1.f / D_MODEL);
  float var = sq * (1.f / D_MODEL) - mean * mean;
  float rstd = rsqrtf(var + 1e-5f);
  for (int i = 0; i < 3; i++) {
    int c = tid + i * 256;
    h2[base + c] = f2bf((v[i] - mean) * rstd * g[c] + be[c]);
  }
}

// ---- partial-sum(2, bf16) + residual + bias -> out fp32 (vectorized x4) ---
__global__ __launch_bounds__(256) void red_ff2(
    const u16* __restrict__ p0, const u16* __restrict__ p1,
    const float* __restrict__ yv,
    const float* __restrict__ bias, float* __restrict__ out) {
  size_t i = ((size_t)blockIdx.x * 256 + threadIdx.x) * 4;
  int col = (int)(i % D_MODEL);
  ushort4 a = *(const ushort4*)(p0 + i);
  ushort4 b = *(const ushort4*)(p1 + i);
  float4 y = *(const float4*)(yv + i);
  float4 o;
  o.x = bf2f(a.x) + bf2f(b.x) + y.x + bias[col];
  o.y = bf2f(a.y) + bf2f(b.y) + y.y + bias[col + 1];
  o.z = bf2f(a.z) + bf2f(b.z) + y.z + bias[col + 2];
  o.w = bf2f(a.w) + bf2f(b.w) + y.w + bias[col + 3];
  *(float4*)(out + i) = o;
}

// ---------------- GEMM: C[M][N] = A[M][K](bf16) * Bt[N][K](bf16)^T ---------
// 64x128 tile, BK=64, 4 waves 2x2 (wave tile 32x64, acc 2x4).
template <int EPI>
__global__ __launch_bounds__(256) void gemm_bt(
    const u16* __restrict__ A, const u16* __restrict__ Bt,
    int M, int N, int K,
    u16* __restrict__ outb, const float* __restrict__ bias,
    float qs, u16* __restrict__ vtp,
    u16* __restrict__ p0, u16* __restrict__ p1) {
  __shared__ __align__(16) u16 lA[64 * 64];    //  8 KB, 8 chunks/row, xor-swz
  __shared__ __align__(16) u16 lB[128 * 64];   // 16 KB
  const int tid = threadIdx.x;
  const int lane = tid & 63, w = tid >> 6;
  const int quad = lane >> 4, l15 = lane & 15;
  const int wm = w >> 1, wn = w & 1;
  const int bm = blockIdx.y, bn = blockIdx.x;
  const int Ksub = K / gridDim.z;
  const int k0 = blockIdx.z * Ksub;

  fx4 acc[2][4] = {};

  for (int kt = k0; kt < k0 + Ksub; kt += 64) {
    __syncthreads();
    #pragma unroll
    for (int t = 0; t < 2; t++) {
      int p = t * 256 + tid;
      int m = p >> 3, qp = p & 7, ql = qp ^ (m & 7);
      async16(A + (size_t)(bm * 64 + m) * K + kt + ql * 8,
              (char*)lA + t * 4096 + w * 1024);
    }
    #pragma unroll
    for (int t = 0; t < 4; t++) {
      int p = t * 256 + tid;
      int n = p >> 3, qp = p & 7, ql = qp ^ (n & 7);
      async16(Bt + (size_t)(bn * 128 + n) * K + kt + ql * 8,
              (char*)lB + t * 4096 + w * 1024);
    }
    __syncthreads();
    #pragma unroll
    for (int kk = 0; kk < 2; kk++) {
      s16x8 af[2], bfr[4];
      #pragma unroll
      for (int i = 0; i < 2; i++) {
        int m = wm * 32 + i * 16 + l15;
        af[i] = *(const s16x8*)((const char*)lA + m * 128 +
                                (((kk * 4 + quad) ^ (m & 7)) * 16));
      }
      #pragma unroll
      for (int j = 0; j < 4; j++) {
        int n = wn * 64 + j * 16 + l15;
        bfr[j] = *(const s16x8*)((const char*)lB + n * 128 +
                                 (((kk * 4 + quad) ^ (n & 7)) * 16));
      }
      #pragma unroll
      for (int i = 0; i < 2; i++)
        #pragma unroll
        for (int j = 0; j < 4; j++)
          acc[i][j] = __builtin_amdgcn_mfma_f32_16x16x32_bf16(af[i], bfr[j], acc[i][j], 0, 0, 0);
    }
  }

  u16* pb = (EPI == 3) ? (blockIdx.z == 0 ? p0 : p1) : nullptr;

  #pragma unroll
  for (int i = 0; i < 2; i++)
    #pragma unroll
    for (int j = 0; j < 4; j++) {
      int row0 = bm * 64 + wm * 32 + i * 16 + quad * 4;
      int col = bn * 128 + wn * 64 + j * 16 + l15;
      if (EPI == 0) {
        if (vtp != nullptr && col >= 1536) {
          // V region -> transposed store: Vt[(b*768 + col-1536)][tok]
          int bb = row0 >> 11, t0 = row0 & 2047;
          ushort4 pk = {f2bf(acc[i][j][0]), f2bf(acc[i][j][1]),
                        f2bf(acc[i][j][2]), f2bf(acc[i][j][3])};
          *(ushort4*)(vtp + ((size_t)(bb * 768 + (col - 1536)) << 11) + t0) = pk;
        } else {
          float sc = (col < 768) ? qs : 1.f;
          for (int r = 0; r < 4; r++)
            outb[(size_t)(row0 + r) * N + col] = f2bf(acc[i][j][r] * sc);
        }
      } else if (EPI == 2) {
        for (int r = 0; r < 4; r++)
          outb[(size_t)(row0 + r) * N + col] = f2bf(fmaxf(acc[i][j][r] + bias[col], 0.f));
      } else {
        for (int r = 0; r < 4; r++)
          pb[(size_t)(row0 + r) * N + col] = f2bf(acc[i][j][r]);
      }
    }
}

// ---------------- Flash attention v7: in-block key split -------------------
// grid (qt=32, bh=24), 512 threads (8 waves). Wave-group g = w>>2 handles
// keys [g*1024, g*1024+1024) (16 iters of 64) with its own sK/sV buffers.
// Wave wg = w&3 owns q rows wg*16..wg*16+15 (q = l15). Groups' half-key O
// and lsum combined in LDS; normalized output via transpose + 16B stores.
__global__ __launch_bounds__(512) void attn_kernel(
    const u16* __restrict__ qkv, const u16* __restrict__ vt,
    const u16* __restrict__ maskadd, u16* __restrict__ out) {
  __shared__ __align__(16) u16 sQ[64 * 64];      //  8 KB
  __shared__ __align__(16) u16 sK[2][64 * 64];   // 16 KB (epi: sT alias)
  __shared__ __align__(16) u16 sV[2][64 * 68];   // 17 KB (epi: cbuf alias)
  __shared__ __align__(16) u16 smask[2048];      //  4 KB bf16 bias
  __shared__ float sL[64];                       // group-1 lsum
  const int bh = blockIdx.y, b = bh / NH, h = bh % NH;
  const int qt = blockIdx.x;
  const int tid = threadIdx.x, lane = tid & 63, w = tid >> 6;
  const int quad = lane >> 4, l15 = lane & 15;
  const int g = w >> 2, wg = w & 3, gtid = tid & 255;

  // stage Q (64 rows x 64): 512 chunks, 1 per thread, swizzle qp ^ (m&7)
  {
    int m = tid >> 3, qp = tid & 7, ql = qp ^ (m & 7);
    async16(qkv + (size_t)(b * TT + qt * 64 + m) * 2304 + h * HS + ql * 8,
            (char*)sQ + w * 1024);
  }
  #pragma unroll
  for (int j = 0; j < 4; j++)
    smask[j * 512 + tid] = maskadd[b * TT + j * 512 + tid];
  // V register prefetch (group keys): rows vr, vr+32; chunk vc
  const int vr = gtid >> 3, vc = gtid & 7;
  const u16* vb0 = vt + ((size_t)bh * HS + vr) * TT + g * 1024;
  const u16* vb1 = vt + ((size_t)bh * HS + vr + 32) * TT + g * 1024;
  s16x8 vcur0 = *(const s16x8*)(vb0 + vc * 8);
  s16x8 vcur1 = *(const s16x8*)(vb1 + vc * 8);
  __syncthreads();

  // Q B-frags: q-row = wg*16 + l15
  const int qrow = wg * 16 + l15;
  s16x8 aq0 = *(const s16x8*)((const char*)sQ + qrow * 128 + ((quad ^ (l15 & 7)) * 16));
  s16x8 aq1 = *(const s16x8*)((const char*)sQ + qrow * 128 + (((4 + quad) ^ (l15 & 7)) * 16));

  const char* pK0 = (const char*)sK[g] + l15 * 128 + ((quad ^ (l15 & 7)) * 16);
  const char* pK1 = (const char*)sK[g] + l15 * 128 + (((4 + quad) ^ (l15 & 7)) * 16);
  const char* pV  = (const char*)sV[g] + l15 * 136 + quad * 8;
  char* vw0 = (char*)sV[g] + vr * 136 + vc * 16;
  char* vw1 = vw0 + 32 * 136;

  float lsum = 0.f;
  fx4 o[4] = {};

  for (int kc = 0; kc < 16; kc++) {
    __syncthreads();
    #pragma unroll
    for (int i = 0; i < 2; i++) {   // stage K chunk (64 keys x 64), per group
      int p = i * 256 + gtid;
      int m = p >> 3, qp = p & 7, ql = qp ^ (m & 7);
      async16(qkv + (size_t)(b * TT + g * 1024 + kc * 64 + m) * 2304 + D_MODEL + h * HS + ql * 8,
              (char*)sK[g] + i * 4096 + wg * 1024);
    }
    *(s16x8*)vw0 = vcur0;           // V tile (136B-padded rows) from regs
    *(s16x8*)vw1 = vcur1;
    __syncthreads();
    int kn = (kc < 15 ? kc + 1 : kc) * 64;
    s16x8 vn0 = *(const s16x8*)(vb0 + kn + vc * 8);
    s16x8 vn1 = *(const s16x8*)(vb1 + kn + vc * 8);

    #pragma unroll
    for (int kt = 0; kt < 4; kt++) {
      ushort4 mk = *(const ushort4*)&smask[g * 1024 + kc * 64 + kt * 16 + quad * 4];
      fx4 s = {bf2f(mk.x), bf2f(mk.y), bf2f(mk.z), bf2f(mk.w)};
      s16x8 ak0 = *(const s16x8*)(pK0 + kt * 2048);
      s16x8 ak1 = *(const s16x8*)(pK1 + kt * 2048);
      s = __builtin_amdgcn_mfma_f32_16x16x32_bf16(ak0, aq0, s, 0, 0, 0);
      s = __builtin_amdgcn_mfma_f32_16x16x32_bf16(ak1, aq1, s, 0, 0, 0);
      float e0 = __builtin_amdgcn_exp2f(s[0]);
      float e1 = __builtin_amdgcn_exp2f(s[1]);
      float e2 = __builtin_amdgcn_exp2f(s[2]);
      float e3 = __builtin_amdgcn_exp2f(s[3]);
      lsum += (e0 + e1) + (e2 + e3);
      s16x4 pB = pack4(e0, e1, e2, e3);
      #pragma unroll
      for (int jv = 0; jv < 4; jv++) {
        s16x4 av = *(const s16x4*)(pV + jv * 2176 + kt * 32);
        o[jv] = __builtin_amdgcn_mfma_f32_16x16x16bf16_1k(av, pB, o[jv], 0, 0, 0);
      }
    }
    vcur0 = vn0; vcur1 = vn1;
  }

  // group-half key-sum per q (= l15): reduce over quads
  lsum += __shfl_xor(lsum, 16);
  lsum += __shfl_xor(lsum, 32);

  // combine the two key-halves in LDS (cbuf over sV, sT over sK — both dead)
  float* cbuf = (float*)sV;    // 64 vd x pitch-66 fp32 = 16,896 B <= 17,408
  u16*   sT   = (u16*)sK;      // 64 vd x pitch-68 u16  =  8,704 B <= 16,384
  __syncthreads();
  if (g == 1) {
    #pragma unroll
    for (int jv = 0; jv < 4; jv++)
      #pragma unroll
      for (int r = 0; r < 4; r++) {
        int vd = jv * 16 + quad * 4 + r;
        cbuf[vd * 66 + wg * 16 + l15] = o[jv][r];
      }
    if (quad == 0) sL[wg * 16 + l15] = lsum;
  }
  __syncthreads();
  if (g == 0) {
    float rinv = 1.f / (lsum + sL[wg * 16 + l15]);
    #pragma unroll
    for (int jv = 0; jv < 4; jv++)
      #pragma unroll
      for (int r = 0; r < 4; r++) {
        int vd = jv * 16 + quad * 4 + r;
        float v = o[jv][r] + cbuf[vd * 66 + wg * 16 + l15];
        sT[vd * 68 + wg * 16 + l15] = f2bf(v * rinv);
      }
  }
  __syncthreads();
  if (tid < 256) {
    int q = tid >> 2, c = tid & 3;
    u16* orow = out + (size_t)(b * TT + qt * 64 + q) * D_MODEL + h * HS + c * 16;
    s16x8 o0, o1;
    #pragma unroll
    for (int i = 0; i < 8; i++) o0[i] = (short)sT[(c * 16 + i) * 68 + q];
    #pragma unroll
    for (int i = 0; i < 8; i++) o1[i] = (short)sT[(c * 16 + 8 + i) * 68 + q];
    *(s16x8*)orow = o0;
    *(s16x8*)(orow + 8) = o1;
  }
}

extern "C" void kernel_launch(void* const* d_in, const int* in_sizes, int n_in,
                              void* d_out, int out_size, void* d_ws, size_t ws_size,
                              hipStream_t stream) {
  const float* x    = (const float*)d_in[0];
  const int*   mask = (const int*)d_in[1];
  const float* Wq   = (const float*)d_in[2];
  const float* Wk   = (const float*)d_in[3];
  const float* Wv   = (const float*)d_in[4];
  const float* Wo   = (const float*)d_in[5];
  const float* bo   = (const float*)d_in[6];
  const float* g1   = (const float*)d_in[7];
  const float* be1  = (const float*)d_in[8];
  const float* g2   = (const float*)d_in[9];
  const float* be2  = (const float*)d_in[10];
  const float* W1   = (const float*)d_in[11];
  const float* bb1  = (const float*)d_in[12];
  const float* W2   = (const float*)d_in[13];
  const float* bb2  = (const float*)d_in[14];
  float* out = (float*)d_out;
  char* ws = (char*)d_ws;

  // workspace carve (bytes), total 64,503,808
  u16*   WqkvT = (u16*)(ws + 0);           //  3,538,944  [2304][768]
  u16*   WoT   = (u16*)(ws + 3538944);     //  1,179,648  [768][768]
  u16*   W1T   = (u16*)(ws + 4718592);     //  4,718,592  [3072][768]
  u16*   W2T   = (u16*)(ws + 9437184);     //  4,718,592  [768][3072]
  u16*   h1    = (u16*)(ws + 14155776);    //  6,291,456  [4096][768]; h2 alias
  u16*   QKV   = (u16*)(ws + 20447232);    // 18,874,368  [4096][2304]
  u16*   Vt    = (u16*)(ws + 39321600);    //  6,291,456  [24][64][2048]
  u16*   attn  = (u16*)(ws + 45613056);    //  6,291,456  [4096][768]
  float* yv    = (float*)(ws + 51904512);  // 12,582,912  [4096][768]
  u16*   mbias = (u16*)(ws + 51904512);    // 8,192 B bf16; dead before yv use
  u16*   h2    = h1;
  u16*   ff1   = QKV;                      // 25.17 MB spans QKV+Vt
  // Wo partials (2 x 6,291,456): QKV span (dead after attn)
  u16* pw0 = (u16*)(ws + 20447232);
  u16* pw1 = (u16*)(ws + 26738688);
  // FF2 partials (2 x 6,291,456)
  u16* pf0 = (u16*)(ws + 0);               // weight-head span (dead)
  u16* pf1 = (u16*)(ws + 14155776);        // h2 (dead after FF1)

  const float QS = 0.05205875399f;  // 768^-0.5 * log2(e)

  preproc<<<11024, 256, 0, stream>>>(x, mask, Wq, Wk, Wv, Wo, W1, W2,
                                     g1, be1, WqkvT, WoT, W1T, W2T, h1, mbias);
  // QKV: Q (scaled), K into QKV buffer; V directly transposed to Vt
  gemm_bt<0><<<dim3(18, 64, 1), 256, 0, stream>>>(h1, WqkvT, 4096, 2304, 768,
      QKV, nullptr, QS, Vt, nullptr, nullptr);
  attn_kernel<<<dim3(32, 24), 512, 0, stream>>>(QKV, Vt, mbias, attn);
  // Wo: split-K=2 -> 768 blocks, Ksub=384
  gemm_bt<3><<<dim3(6, 64, 2), 256, 0, stream>>>(attn, WoT, 4096, 768, 768,
      nullptr, nullptr, 1.f, nullptr, pw0, pw1);
  red_wo_ln<<<4096, 256, 0, stream>>>(pw0, pw1, x, bo, g2, be2, yv, h2);
  gemm_bt<2><<<dim3(24, 64, 1), 256, 0, stream>>>(h2, W1T, 4096, 3072, 768,
      ff1, bb1, 1.f, nullptr, nullptr, nullptr);
  // FF2: split-K=2 -> 768 blocks, Ksub=1536
  gemm_bt<3><<<dim3(6, 64, 2), 256, 0, stream>>>(ff1, W2T, 4096, 768, 3072,
      nullptr, nullptr, 1.f, nullptr, pf0, pf1);
  red_ff2<<<3072, 256, 0, stream>>>(pf0, pf1, yv, bb2, out);
}